// Round 7
// baseline (16614.331 us; speedup 1.0000x reference)
//
#include <hip/hip_runtime.h>
#include <math.h>

typedef unsigned short u16;
typedef __attribute__((ext_vector_type(8))) short short8;
typedef __attribute__((ext_vector_type(4))) float float4v;

#define HH   512
#define BB   256
#define TLEN 512
#define DD   64

__device__ __forceinline__ float sigm(float x) { return 1.0f / (1.0f + __expf(-x)); }

__device__ __forceinline__ u16 bf16rn(float v) {
    unsigned u = __float_as_uint(v);
    u += 0x7fffu + ((u >> 16) & 1u);
    return (u16)(u >> 16);
}
__device__ __forceinline__ float bf16tf(u16 h) { return __uint_as_float(((unsigned)h) << 16); }

__device__ __forceinline__ float4v mfma16(short8 a, short8 b, float4v c) {
    return __builtin_amdgcn_mfma_f32_16x16x32_bf16(a, b, c, 0, 0, 0);
}

// ---------------- precompute kernels ----------------

__global__ __launch_bounds__(256) void split_kernel(const float* __restrict__ src,
                                                    u16* __restrict__ hi, u16* __restrict__ lo, int n)
{
    for (int i = blockIdx.x * 256 + threadIdx.x; i < n; i += gridDim.x * 256) {
        float v = src[i];
        u16 h = bf16rn(v);
        hi[i] = h;
        lo[i] = bf16rn(v - bf16tf(h));
    }
}

// x[B][T*D] -> xT[t][m][d] hi/lo split
__global__ __launch_bounds__(256) void txpose_kernel(const float* __restrict__ x,
                                                     u16* __restrict__ hi, u16* __restrict__ lo)
{
    const int N = BB * TLEN * DD;
    for (int i = blockIdx.x * 256 + threadIdx.x; i < N; i += gridDim.x * 256) {
        int d = i & 63, m = (i >> 6) & 255, t = i >> 14;
        float v = x[(size_t)m * (TLEN * DD) + t * DD + d];
        u16 h = bf16rn(v);
        hi[i] = h;
        lo[i] = bf16rn(v - bf16tf(h));
    }
}

__global__ __launch_bounds__(256) void zero_kernel(unsigned* p, int n)
{
    int i = blockIdx.x * 256 + threadIdx.x;
    if (i < n) p[i] = 0u;
}

// ---------------- half-pass: batched A loads (forced MLP) + MFMA from LDS B ----------------
// Wave tile 32m x 32n. NCH chunks of k=32; first NX chunks read A from xT (stride DD),
// rest from h (stride HH) starting at h-chunk hbase. B fragments come from LDS at
// chunk index coff+c. sched_barrier(0) pins: all loads issued BEFORE any MFMA,
// so the 4*NCH loads are in flight together (one latency exposure per half-pass).
template <int NCH, int NX>
__device__ __forceinline__ void halfpass(
    const u16* __restrict__ axh, const u16* __restrict__ axl, const size_t (&xoff)[2],
    const u16* __restrict__ ahh, const u16* __restrict__ ahl, const size_t (&hoff)[2], int hbase,
    const short* __restrict__ sB, int bbase, int coff, float4v (&acc)[2][2])
{
    short8 Ah[NCH][2], Al[NCH][2];
#pragma unroll
    for (int c = 0; c < NCH; ++c)
#pragma unroll
        for (int mt = 0; mt < 2; ++mt) {
            if (c < NX) {
                Ah[c][mt] = *(const short8*)(axh + xoff[mt] + (size_t)c * 32);
                Al[c][mt] = *(const short8*)(axl + xoff[mt] + (size_t)c * 32);
            } else {
                Ah[c][mt] = *(const short8*)(ahh + hoff[mt] + (size_t)(hbase + c - NX) * 32);
                Al[c][mt] = *(const short8*)(ahl + hoff[mt] + (size_t)(hbase + c - NX) * 32);
            }
        }
    __builtin_amdgcn_sched_barrier(0);   // loads may not sink past this point
#pragma unroll
    for (int c = 0; c < NCH; ++c) {
        const int cb = coff + c;
        short8 bh[2], bl[2];
#pragma unroll
        for (int nt = 0; nt < 2; ++nt) {
            bh[nt] = *(const short8*)(sB + bbase + ((cb * 2 + nt) * 2 + 0) * 512);
            bl[nt] = *(const short8*)(sB + bbase + ((cb * 2 + nt) * 2 + 1) * 512);
        }
#pragma unroll
        for (int mt = 0; mt < 2; ++mt)
#pragma unroll
            for (int nt = 0; nt < 2; ++nt) {
                acc[mt][nt] = mfma16(Ah[c][mt], bh[nt], acc[mt][nt]);
                acc[mt][nt] = mfma16(Ah[c][mt], bl[nt], acc[mt][nt]);
                acc[mt][nt] = mfma16(Al[c][mt], bh[nt], acc[mt][nt]);
            }
    }
}

// ---------------- grid barrier (r5/r6-proven): distributed flags, relaxed polling ----------------

__device__ __forceinline__ void gridbar(unsigned* flags, unsigned* gen,
                                        unsigned it, int tid, int bid)
{
    __syncthreads();
    if (tid == 0) {
        __threadfence();
        __hip_atomic_store(&flags[bid * 32], it + 1, __ATOMIC_RELEASE, __HIP_MEMORY_SCOPE_AGENT);
    }
    if (bid == 0) {
        if (tid < 256) {
            while (__hip_atomic_load(&flags[tid * 32], __ATOMIC_RELAXED, __HIP_MEMORY_SCOPE_AGENT) < it + 1)
                __builtin_amdgcn_s_sleep(1);
        }
        __syncthreads();
        if (tid == 0)
            __hip_atomic_store(gen, it + 1, __ATOMIC_RELEASE, __HIP_MEMORY_SCOPE_AGENT);
    }
    if (tid == 0) {
        while (__hip_atomic_load(gen, __ATOMIC_RELAXED, __HIP_MEMORY_SCOPE_AGENT) < it + 1)
            __builtin_amdgcn_s_sleep(1);
        __threadfence();
    }
    __syncthreads();
}

// ---------------- persistent kernel: LDS-resident weights, batched A loads ----------------
// 256 blocks x 512 threads, 1 block/CU (147456 B LDS).
// bid<128 -> L0; else L1. q=bid&127: jslice=q>>1 (8 units), mhalf=q&1 (128 rows).
// bid%8 fixes XCD; mhalf=q&1 => all blocks on an XCD share the same m-half (L2 locality).
// 8 waves = 4 msegs (32 rows) x 2 khalfs. Weights in LDS in MFMA-frag order.

__global__ __launch_bounds__(512, 2) void lstm_persist(
    const u16* __restrict__ xTh, const u16* __restrict__ xTl,
    const u16* __restrict__ wih0h, const u16* __restrict__ wih0l,
    const u16* __restrict__ whh0h, const u16* __restrict__ whh0l,
    const u16* __restrict__ wih1h, const u16* __restrict__ wih1l,
    const u16* __restrict__ whh1h, const u16* __restrict__ whh1l,
    const float* __restrict__ bi0, const float* __restrict__ bh0,
    const float* __restrict__ bi1, const float* __restrict__ bh1,
    u16* h0hi0, u16* h0lo0, u16* h0hi1, u16* h0lo1,
    u16* h1hi0, u16* h1lo0, u16* h1hi1, u16* h1lo1,
    float* h1last, unsigned* flags)
{
    __shared__ short smem[73728];          // 128 KB weights + 16 KB staging
    float* sEp = (float*)(smem + 65536);

    const int tid  = threadIdx.x;
    const int lane = tid & 63;
    const int wv   = tid >> 6;
    const int mseg = wv & 3, khalf = wv >> 2;
    const int bid  = blockIdx.x;
    const bool role1 = (bid >= 128);
    const int q = bid & 127;
    const int jslice = q >> 1, mhalf = q & 1;
    const int m0 = mhalf * 128, j0 = jslice * 8;
    const int nsel = lane & 15, kq = (lane >> 4) * 8;
    unsigned* gen = flags + 8192;

    // ---- weight preload to LDS (once), MFMA-frag order, lane-linear ----
    if (!role1) {
        for (int g = wv; g < 72; g += 8) {
            int c = g >> 2, nt = (g >> 1) & 1, hl = g & 1;
            int n = nt * 16 + nsel;
            int grow = (n >> 3) * HH + j0 + (n & 7);
            const u16* src; size_t off;
            if (c < 2) { src = hl ? wih0l : wih0h; off = (size_t)grow * DD + c * 32 + kq; }
            else       { src = hl ? whh0l : whh0h; off = (size_t)grow * HH + (size_t)(c - 2) * 32 + kq; }
            *(short8*)&smem[g * 512 + lane * 8] = *(const short8*)(src + off);
        }
    } else {
        for (int g = wv; g < 128; g += 8) {
            int khw = g >> 6, c = (g >> 2) & 15, nt = (g >> 1) & 1, hl = g & 1;
            int n = nt * 16 + nsel;
            int grow = (n >> 3) * HH + j0 + (n & 7);
            const u16* src = khw ? (hl ? whh1l : whh1h) : (hl ? wih1l : wih1h);
            *(short8*)&smem[g * 512 + lane * 8] = *(const short8*)(src + (size_t)grow * HH + (size_t)c * 32 + kq);
        }
    }
    __syncthreads();

    // ---- constants ----
    const int ejl = lane & 7;
    const int jglob = j0 + ejl;
    const float* pbi = role1 ? bi1 : bi0;
    const float* pbh = role1 ? bh1 : bh0;
    float bias4[4];
#pragma unroll
    for (int b = 0; b < 4; ++b) bias4[b] = pbi[b * HH + jglob] + pbh[b * HH + jglob];

    size_t hoff[2], xoffb[2];
#pragma unroll
    for (int mt = 0; mt < 2; ++mt) {
        const int arow = m0 + mseg * 32 + mt * 16 + nsel;
        hoff[mt]  = (size_t)arow * HH + kq + ((!role1 && khalf) ? 7 * 32 : 0);
        xoffb[mt] = (size_t)arow * DD + kq;
    }
    const int bbase = (role1 ? khalf * 16 : (khalf ? 9 : 0)) * 2048 + lane * 8;

    float creg[2][4] = {{0.f,0.f,0.f,0.f},{0.f,0.f,0.f,0.f}};

    for (int it = 0; it <= TLEN; ++it) {
        const int rb = it & 1;
        const u16* h0r_h = rb ? h0hi1 : h0hi0;
        const u16* h0r_l = rb ? h0lo1 : h0lo0;
        const u16* h1r_h = rb ? h1hi1 : h1hi0;
        const u16* h1r_l = rb ? h1lo1 : h1lo0;
        u16* h0w_h = rb ? h0hi0 : h0hi1;
        u16* h0w_l = rb ? h0lo0 : h0lo1;
        u16* h1w_h = rb ? h1hi0 : h1hi1;
        u16* h1w_l = rb ? h1lo0 : h1lo1;
        const bool active = role1 ? (it > 0) : (it < TLEN);

        if (active) {
            float4v acc[2][2];
#pragma unroll
            for (int mt = 0; mt < 2; ++mt)
#pragma unroll
                for (int nt = 0; nt < 2; ++nt) { acc[mt][nt][0]=0.f; acc[mt][nt][1]=0.f; acc[mt][nt][2]=0.f; acc[mt][nt][3]=0.f; }

            if (role1) {
                // khalf=0: h0 . Wih1 (16 chunks); khalf=1: h1 . Whh1 (16 chunks)
                const u16* ah = khalf ? h1r_h : h0r_h;
                const u16* al = khalf ? h1r_l : h0r_l;
                halfpass<8, 0>(nullptr, nullptr, hoff, ah, al, hoff, 0, smem, bbase, 0, acc);
                halfpass<8, 0>(nullptr, nullptr, hoff, ah, al, hoff, 8, smem, bbase, 8, acc);
            } else if (khalf == 0) {
                // x (2 chunks) + h0 chunks [0,7)
                size_t xoff[2] = { xoffb[0] + (size_t)it * (BB * DD), xoffb[1] + (size_t)it * (BB * DD) };
                halfpass<5, 2>(xTh, xTl, xoff, h0r_h, h0r_l, hoff, 0, smem, bbase, 0, acc);
                halfpass<4, 0>(nullptr, nullptr, xoff, h0r_h, h0r_l, hoff, 3, smem, bbase, 5, acc);
            } else {
                // h0 chunks [7,16) (hoff carries +224)
                halfpass<5, 0>(nullptr, nullptr, xoffb, h0r_h, h0r_l, hoff, 0, smem, bbase, 0, acc);
                halfpass<4, 0>(nullptr, nullptr, xoffb, h0r_h, h0r_l, hoff, 5, smem, bbase, 5, acc);
            }

            if (khalf == 1) {    // stage partials (lane-linear, conflict-free)
#pragma unroll
                for (int mt = 0; mt < 2; ++mt)
#pragma unroll
                    for (int nt = 0; nt < 2; ++nt)
#pragma unroll
                        for (int r = 0; r < 4; ++r)
                            sEp[((((mseg * 2 + mt) * 2 + nt) * 4) + r) * 64 + lane] = acc[mt][nt][r];
            }
            __syncthreads();
            if (khalf == 0) {
                u16* wh = role1 ? h1w_h : h0w_h;
                u16* wl = role1 ? h1w_l : h0w_l;
#pragma unroll
                for (int mt = 0; mt < 2; ++mt)
#pragma unroll
                    for (int r = 0; r < 4; ++r) {
                        float v0 = acc[mt][0][r] + sEp[((((mseg * 2 + mt) * 2 + 0) * 4) + r) * 64 + lane];
                        float v1 = acc[mt][1][r] + sEp[((((mseg * 2 + mt) * 2 + 1) * 4) + r) * 64 + lane];
                        float p0 = __shfl_xor(v0, 8, 64);
                        float p1 = __shfl_xor(v1, 8, 64);
                        if (nsel < 8) {
                            float gi = v0 + bias4[0];
                            float gf = p0 + bias4[1];
                            float gG = v1 + bias4[2];
                            float go = p1 + bias4[3];
                            float cn = sigm(gf) * creg[mt][r] + sigm(gi) * tanhf(gG);
                            float h  = sigm(go) * tanhf(cn);
                            creg[mt][r] = cn;
                            const int m = m0 + mseg * 32 + mt * 16 + (lane >> 4) * 4 + r;
                            const size_t off = (size_t)m * HH + jglob;
                            u16 hv = bf16rn(h);
                            wh[off] = hv;
                            wl[off] = bf16rn(h - bf16tf(hv));
                            if (role1 && it == TLEN) h1last[off] = h;
                        }
                    }
            }
        }
        if (it < TLEN) gridbar(flags, gen, (unsigned)it, tid, bid);
    }
}

// ---------------- FC head (proven) ----------------

template <int MODE>
__global__ __launch_bounds__(256) void gemm_step(
    const float* __restrict__ A1, int lda1, int K1, const float* __restrict__ W1,
    const float* __restrict__ b1, float* __restrict__ h_out)
{
    __shared__ float sA[16][33];
    __shared__ float sW[128][33];

    const int tid = threadIdx.x;
    const int tj  = tid & 31;
    const int tg  = tid >> 5;
    const int m0  = blockIdx.x * 16;
    const int j0  = blockIdx.y * 128;

    float acc[2][4] = {{0.f, 0.f, 0.f, 0.f}, {0.f, 0.f, 0.f, 0.f}};

    for (int kb = 0; kb < K1; kb += 32) {
        __syncthreads();
        {
            int idxq = tid;
#pragma unroll
            for (int r = 0; r < 2; ++r, idxq += 256) {
                int row = idxq >> 5, col = idxq & 31;
                sA[row][col] = A1[(m0 + row) * lda1 + kb + col];
            }
        }
        {
#pragma unroll
            for (int i = 0; i < 16; ++i) {
                int idxq = i * 256 + tid;
                int row = idxq >> 5, col = idxq & 31;
                sW[row][col] = W1[(j0 + row) * K1 + kb + col];
            }
        }
        __syncthreads();
#pragma unroll
        for (int k = 0; k < 32; ++k) {
            float a0 = sA[tg][k];
            float a1 = sA[tg + 8][k];
            float w0 = sW[tj][k];
            float w1 = sW[32 + tj][k];
            float w2 = sW[64 + tj][k];
            float w3 = sW[96 + tj][k];
            acc[0][0] += a0 * w0; acc[0][1] += a0 * w1;
            acc[0][2] += a0 * w2; acc[0][3] += a0 * w3;
            acc[1][0] += a1 * w0; acc[1][1] += a1 * w1;
            acc[1][2] += a1 * w2; acc[1][3] += a1 * w3;
        }
    }

#pragma unroll
    for (int r = 0; r < 2; ++r) {
        int m = m0 + tg + r * 8;
#pragma unroll
        for (int p = 0; p < 4; ++p) {
            int nn = j0 + p * 32 + tj;
            float v = acc[r][p] + b1[nn];
            h_out[m * HH + nn] = fmaxf(v, 0.f);
        }
    }
}

__global__ __launch_bounds__(64) void fc2_kernel(
    const float* __restrict__ z, const float* __restrict__ W,
    const float* __restrict__ b, float* __restrict__ out)
{
    int m = blockIdx.x;
    int lane = threadIdx.x;
    float zr[8];
#pragma unroll
    for (int u = 0; u < 8; ++u) zr[u] = z[m * 512 + u * 64 + lane];
#pragma unroll
    for (int o = 0; o < 8; ++o) {
        float s = 0.f;
#pragma unroll
        for (int u = 0; u < 8; ++u) s += zr[u] * W[o * 512 + u * 64 + lane];
#pragma unroll
        for (int off = 32; off > 0; off >>= 1) s += __shfl_down(s, off);
        if (lane == 0) out[m * 8 + o] = s + b[o];
    }
}

__global__ __launch_bounds__(256) void zero_f_kernel(float* p, int n)
{
    int i = blockIdx.x * 256 + threadIdx.x;
    if (i < n) p[i] = 0.f;
}

// fp32 LSTM step for fallback path
__global__ __launch_bounds__(256) void gemm_lstm_f32(
    const float* __restrict__ A1, int lda1, int K1, const float* __restrict__ W1,
    const float* __restrict__ A2, int K2, const float* __restrict__ W2,
    const float* __restrict__ b1, const float* __restrict__ b2,
    const float* __restrict__ c_in, float* __restrict__ c_out,
    float* __restrict__ h_out)
{
    __shared__ float sA[16][33];
    __shared__ float sW[128][33];

    const int tid = threadIdx.x;
    const int tj  = tid & 31;
    const int tg  = tid >> 5;
    const int m0  = blockIdx.x * 16;
    const int j0  = blockIdx.y * 32;

    float acc[2][4] = {{0.f, 0.f, 0.f, 0.f}, {0.f, 0.f, 0.f, 0.f}};

    for (int seg = 0; seg < 2; ++seg) {
        const float* A  = seg ? A2 : A1;
        const float* W  = seg ? W2 : W1;
        const int    K  = seg ? K2 : K1;
        const int    ld = seg ? HH : lda1;
        for (int kb = 0; kb < K; kb += 32) {
            __syncthreads();
            {
                int idxq = tid;
#pragma unroll
                for (int r = 0; r < 2; ++r, idxq += 256) {
                    int row = idxq >> 5, col = idxq & 31;
                    sA[row][col] = A[(m0 + row) * ld + kb + col];
                }
            }
            {
#pragma unroll
                for (int i = 0; i < 16; ++i) {
                    int idxq = i * 256 + tid;
                    int row = idxq >> 5, col = idxq & 31;
                    int grw = (row >> 5) * HH + j0 + (row & 31);
                    sW[row][col] = W[grw * K + kb + col];
                }
            }
            __syncthreads();
#pragma unroll
            for (int k = 0; k < 32; ++k) {
                float a0 = sA[tg][k];
                float a1 = sA[tg + 8][k];
                float w0 = sW[tj][k];
                float w1 = sW[32 + tj][k];
                float w2 = sW[64 + tj][k];
                float w3 = sW[96 + tj][k];
                acc[0][0] += a0 * w0; acc[0][1] += a0 * w1;
                acc[0][2] += a0 * w2; acc[0][3] += a0 * w3;
                acc[1][0] += a1 * w0; acc[1][1] += a1 * w1;
                acc[1][2] += a1 * w2; acc[1][3] += a1 * w3;
            }
        }
    }

    const int j = j0 + tj;
    const float bi = b1[j] + b2[j];
    const float bf = b1[HH + j] + b2[HH + j];
    const float bg = b1[2 * HH + j] + b2[2 * HH + j];
    const float bo = b1[3 * HH + j] + b2[3 * HH + j];
#pragma unroll
    for (int r = 0; r < 2; ++r) {
        int m = m0 + tg + r * 8;
        float gi = acc[r][0] + bi;
        float gf = acc[r][1] + bf;
        float gg = acc[r][2] + bg;
        float go = acc[r][3] + bo;
        float cp = c_in[m * HH + j];
        float c  = sigm(gf) * cp + sigm(gi) * tanhf(gg);
        float h  = sigm(go) * tanhf(c);
        c_out[m * HH + j] = c;
        h_out[m * HH + j] = h;
    }
}

// ---------------- host ----------------

extern "C" void kernel_launch(void* const* d_in, const int* in_sizes, int n_in,
                              void* d_out, int out_size, void* d_ws, size_t ws_size,
                              hipStream_t stream)
{
    const float* x     = (const float*)d_in[0];
    const float* W_ih0 = (const float*)d_in[1];
    const float* W_hh0 = (const float*)d_in[2];
    const float* b_ih0 = (const float*)d_in[3];
    const float* b_hh0 = (const float*)d_in[4];
    const float* W_ih1 = (const float*)d_in[5];
    const float* W_hh1 = (const float*)d_in[6];
    const float* b_ih1 = (const float*)d_in[7];
    const float* b_hh1 = (const float*)d_in[8];
    const float* W_fc1 = (const float*)d_in[9];
    const float* b_fc1 = (const float*)d_in[10];
    const float* W_fc2 = (const float*)d_in[11];
    const float* b_fc2 = (const float*)d_in[12];
    float* out = (float*)d_out;

    const size_t S  = (size_t)BB * HH;        // 131072 elems
    const size_t SB = S * sizeof(u16);        // 262144 B
    const size_t SF = S * sizeof(float);      // 524288 B
    const size_t XN = (size_t)BB * TLEN * DD; // 8388608 elems
    const size_t FLAGB = (8192 + 32) * 4;

    const size_t NEED = FLAGB + 8 * SB + 2 * SF + 2 * XN * 2 +
                        2 * 131072 * 2 + 6 * 1048576 * 2;

    if (ws_size >= NEED) {
        char* W = (char*)d_ws;
        size_t o = 0;
        unsigned* flags = (unsigned*)(W + o); o += FLAGB;
        u16* h0hi0 = (u16*)(W + o); o += SB;
        u16* h0lo0 = (u16*)(W + o); o += SB;
        u16* h1hi1 = (u16*)(W + o); o += SB;
        u16* h1lo1 = (u16*)(W + o); o += SB;
        const size_t ZBYTES = o;
        u16* h0hi1 = (u16*)(W + o); o += SB;
        u16* h0lo1 = (u16*)(W + o); o += SB;
        u16* h1hi0 = (u16*)(W + o); o += SB;
        u16* h1lo0 = (u16*)(W + o); o += SB;
        float* h1last = (float*)(W + o); o += SF;
        float* zfc    = (float*)(W + o); o += SF;
        u16* xTh = (u16*)(W + o); o += XN * 2;
        u16* xTl = (u16*)(W + o); o += XN * 2;
        u16* wih0h = (u16*)(W + o); o += 131072 * 2;
        u16* wih0l = (u16*)(W + o); o += 131072 * 2;
        u16* whh0h = (u16*)(W + o); o += 1048576 * 2;
        u16* whh0l = (u16*)(W + o); o += 1048576 * 2;
        u16* wih1h = (u16*)(W + o); o += 1048576 * 2;
        u16* wih1l = (u16*)(W + o); o += 1048576 * 2;
        u16* whh1h = (u16*)(W + o); o += 1048576 * 2;
        u16* whh1l = (u16*)(W + o); o += 1048576 * 2;

        zero_kernel<<<(int)((ZBYTES / 4 + 255) / 256), 256, 0, stream>>>((unsigned*)d_ws, (int)(ZBYTES / 4));
        txpose_kernel<<<2048, 256, 0, stream>>>(x, xTh, xTl);
        split_kernel<<<512, 256, 0, stream>>>(W_ih0, wih0h, wih0l, 131072);
        split_kernel<<<2048, 256, 0, stream>>>(W_hh0, whh0h, whh0l, 1048576);
        split_kernel<<<2048, 256, 0, stream>>>(W_ih1, wih1h, wih1l, 1048576);
        split_kernel<<<2048, 256, 0, stream>>>(W_hh1, whh1h, whh1l, 1048576);

        lstm_persist<<<256, 512, 0, stream>>>(
            xTh, xTl,
            wih0h, wih0l, whh0h, whh0l,
            wih1h, wih1l, whh1h, whh1l,
            b_ih0, b_hh0, b_ih1, b_hh1,
            h0hi0, h0lo0, h0hi1, h0lo1,
            h1hi0, h1lo0, h1hi1, h1lo1,
            h1last, flags);

        dim3 grid_fc1(BB / 16, 512 / 128);
        gemm_step<1><<<grid_fc1, 256, 0, stream>>>(h1last, HH, HH, W_fc1, b_fc1, zfc);
        fc2_kernel<<<BB, 64, 0, stream>>>(zfc, W_fc2, b_fc2, out);
        return;
    }

    // -------- fallback: fp32 path --------
    float* wsf = (float*)d_ws;
    float* h0a = wsf + 0 * S;
    float* c0  = wsf + 1 * S;
    float* h1a = wsf + 2 * S;
    float* c1  = wsf + 3 * S;
    float* h0b = wsf + 4 * S;
    float* h1b = wsf + 5 * S;
    float* zb  = wsf + 6 * S;
    float* h0buf[2] = {h0a, h0b};
    float* h1buf[2] = {h1a, h1b};

    zero_f_kernel<<<(int)((4 * S + 255) / 256), 256, 0, stream>>>(wsf, (int)(4 * S));

    dim3 grid_lstm(BB / 16, HH / 32);
    for (int t = 0; t < TLEN; ++t) {
        const float* xt = x + (size_t)t * DD;
        gemm_lstm_f32<<<grid_lstm, 256, 0, stream>>>(
            xt, TLEN * DD, DD, W_ih0,
            h0buf[t & 1], HH, W_hh0,
            b_ih0, b_hh0, c0, c0, h0buf[(t + 1) & 1]);
        gemm_lstm_f32<<<grid_lstm, 256, 0, stream>>>(
            h0buf[(t + 1) & 1], HH, HH, W_ih1,
            h1buf[t & 1], HH, W_hh1,
            b_ih1, b_hh1, c1, c1, h1buf[(t + 1) & 1]);
    }
    dim3 grid_fc1(BB / 16, 512 / 128);
    gemm_step<1><<<grid_fc1, 256, 0, stream>>>(h1buf[0], HH, HH, W_fc1, b_fc1, zb);
    fc2_kernel<<<BB, 64, 0, stream>>>(zb, W_fc2, b_fc2, out);
}